// Round 1
// baseline (267.669 us; speedup 1.0000x reference)
//
#include <hip/hip_runtime.h>

#define NSUB 48      // pupil nonzero rows/cols are [8,56) of the 64x64 grid
#define J0   8
#define PIF  3.14159265358979323846f

// Build twiddle table tw[t] = e^{2*pi*i*t/256} and pupil P[j,k] (stored k-major:
// P[kk*48+jj]) into LDS. P[j,k] = mag * e^{i*(pupil_phase + prop*z - (2pi/256)((j-32)x+(k-32)y))}
__device__ __forceinline__ void build_pupil_and_tw(
    int tid, float x, float y, float z,
    const float* __restrict__ phase_in,
    float* __restrict__ Pre, float* __restrict__ Pim,
    float* __restrict__ twc, float* __restrict__ tws)
{
    {
        float s, c;
        __sincosf((float)tid * (PIF / 128.0f), &s, &c);
        twc[tid] = c; tws[tid] = s;
    }
    const float c1 = PIF / 128.0f;  // 2*pi/256
    for (int idx = tid; idx < NSUB * NSUB; idx += 256) {
        int jj = idx / NSUB;
        int kk = idx - jj * NSUB;
        int j = jj + J0, k = kk + J0;
        float us = ((float)(2 * j) * (1.0f / 63.0f) - 1.0f) * (4.0f / 3.0f);
        float vs = ((float)(2 * k) * (1.0f / 63.0f) - 1.0f) * (4.0f / 3.0f);
        float r2 = us * us + vs * vs;
        float re = 0.0f, im = 0.0f;
        if (r2 <= 1.0f) {
            float prop = sqrtf(fmaxf(1.0f - r2, 0.0f));
            float ph = phase_in[j * 64 + k] + prop * z
                       - c1 * ((float)(j - 32) * x + (float)(k - 32) * y);
            float s, c;
            __sincosf(ph, &s, &c);
            re = c; im = s;
        }
        Pre[kk * NSUB + jj] = re;  // k-major for conflict-free G-stage reads
        Pim[kk * NSUB + jj] = im;
    }
}

// Kernel 1: per (pair, v-chunk) block. Computes |F[u,v]|^2 over the full 256x256
// grid (u = tid, v in chunk of 64) and atomicMax's the per-pair maximum.
__global__ __launch_bounds__(256, 4)
void psf_max_kernel(const float* __restrict__ X, const float* __restrict__ Y,
                    const float* __restrict__ Z,
                    const float* __restrict__ phase_in,
                    float* __restrict__ maxws)
{
    __shared__ float Pre[NSUB * NSUB], Pim[NSUB * NSUB];
    __shared__ float twc[256], tws[256];
    __shared__ __align__(16) float Gre[NSUB * 4];
    __shared__ __align__(16) float Gim[NSUB * 4];
    __shared__ float red[4];

    int tid = threadIdx.x;
    int pair = blockIdx.x >> 2;
    int chunk = blockIdx.x & 3;
    float x = X[pair], y = Y[pair], z = Z[pair];

    build_pupil_and_tw(tid, x, y, z, phase_in, Pre, Pim, twc, tws);
    __syncthreads();

    // Per-thread rotation constants for F stage (u = tid):
    // step = e^{2*pi*i*u/256}, w8 = e^{2*pi*i*8u/256}
    float sc_s, sc_c, s8, c8;
    __sincosf((float)tid * (PIF / 128.0f), &sc_s, &sc_c);
    __sincosf((float)tid * (PIF / 16.0f), &s8, &c8);

    int jj48 = tid % 48;
    int vv48 = tid / 48;

    float lmax = 0.0f;
    int v0 = chunk * 64;
    for (int bb = 0; bb < 16; ++bb) {
        int vb = v0 + bb * 4;
        // ---- G stage: G[j,v] = sum_k P[j,k] * e^{2 pi i k v / 256}
        if (tid < 192) {
            int v = vb + vv48;
            float gre = 0.0f, gim = 0.0f;
            #pragma unroll 4
            for (int kk = 0; kk < NSUB; ++kk) {
                int t = ((kk + J0) * v) & 255;
                float pr = Pre[kk * NSUB + jj48];
                float pi = Pim[kk * NSUB + jj48];
                float tc = twc[t], ts = tws[t];
                gre = fmaf(pr, tc, fmaf(-pi, ts, gre));
                gim = fmaf(pr, ts, fmaf(pi, tc, gim));
            }
            Gre[jj48 * 4 + vv48] = gre;
            Gim[jj48 * 4 + vv48] = gim;
        }
        __syncthreads();
        // ---- F stage: F[u,v] = sum_j G[j,v] * e^{2 pi i j u / 256}
        float wr = c8, wi = s8;
        float a0r = 0, a0i = 0, a1r = 0, a1i = 0;
        float a2r = 0, a2i = 0, a3r = 0, a3i = 0;
        #pragma unroll 4
        for (int jj = 0; jj < NSUB; ++jj) {
            float4 gr = ((const float4*)Gre)[jj];
            float4 gi = ((const float4*)Gim)[jj];
            a0r = fmaf(gr.x, wr, fmaf(-gi.x, wi, a0r));
            a0i = fmaf(gr.x, wi, fmaf( gi.x, wr, a0i));
            a1r = fmaf(gr.y, wr, fmaf(-gi.y, wi, a1r));
            a1i = fmaf(gr.y, wi, fmaf( gi.y, wr, a1i));
            a2r = fmaf(gr.z, wr, fmaf(-gi.z, wi, a2r));
            a2i = fmaf(gr.z, wi, fmaf( gi.z, wr, a2i));
            a3r = fmaf(gr.w, wr, fmaf(-gi.w, wi, a3r));
            a3i = fmaf(gr.w, wi, fmaf( gi.w, wr, a3i));
            float nwr = fmaf(wr, sc_c, -(wi * sc_s));
            float nwi = fmaf(wr, sc_s,  (wi * sc_c));
            wr = nwr; wi = nwi;
        }
        float m01 = fmaxf(fmaf(a0r, a0r, a0i * a0i), fmaf(a1r, a1r, a1i * a1i));
        float m23 = fmaxf(fmaf(a2r, a2r, a2i * a2i), fmaf(a3r, a3r, a3i * a3i));
        lmax = fmaxf(lmax, fmaxf(m01, m23));
        __syncthreads();
    }

    // Block max-reduce, then device-scope atomicMax (uint trick: valid for floats >= 0)
    for (int off = 32; off > 0; off >>= 1)
        lmax = fmaxf(lmax, __shfl_down(lmax, off, 64));
    if ((tid & 63) == 0) red[tid >> 6] = lmax;
    __syncthreads();
    if (tid == 0) {
        float m = fmaxf(fmaxf(red[0], red[1]), fmaxf(red[2], red[3]));
        atomicMax((unsigned int*)&maxws[pair], __float_as_uint(m));
    }
}

// Kernel 2: per-pair block. Recomputes only the cropped 64x64 field values
// (crop index a -> u=(a+224)&255), normalizes by the pair max, applies A/bg/mask,
// accumulates over n into out via atomicAdd.
__global__ __launch_bounds__(256, 4)
void psf_crop_kernel(const float* __restrict__ X, const float* __restrict__ Y,
                     const float* __restrict__ Z, const float* __restrict__ Aamp,
                     const float* __restrict__ BG, const float* __restrict__ Pmask,
                     const float* __restrict__ phase_in,
                     const float* __restrict__ maxws,
                     float* __restrict__ out)
{
    int pair = blockIdx.x;
    if (Pmask[pair] <= 0.5f) return;  // uniform across block: safe early-exit

    __shared__ float Pre[NSUB * NSUB], Pim[NSUB * NSUB];
    __shared__ float twc[256], tws[256];
    __shared__ __align__(16) float Gre[NSUB * 4];
    __shared__ __align__(16) float Gim[NSUB * 4];

    int tid = threadIdx.x;
    float x = X[pair], y = Y[pair], z = Z[pair];
    build_pupil_and_tw(tid, x, y, z, phase_in, Pre, Pim, twc, tws);
    __syncthreads();

    float scale = Aamp[pair] / maxws[pair];
    float bgv = BG[pair];

    int a = tid & 63, cc = tid >> 6;
    int u = (a + 224) & 255;
    float sc_s, sc_c, s8, c8;
    __sincosf((float)u * (PIF / 128.0f), &sc_s, &sc_c);
    __sincosf((float)u * (PIF / 16.0f), &s8, &c8);

    int jj48 = tid % 48;
    int vv48 = tid / 48;
    float* outb = out + ((pair >> 2) << 12);  // b * 64*64

    for (int cb = 0; cb < 64; cb += 4) {
        if (tid < 192) {
            int v = ((cb + vv48) + 224) & 255;
            float gre = 0.0f, gim = 0.0f;
            #pragma unroll 4
            for (int kk = 0; kk < NSUB; ++kk) {
                int t = ((kk + J0) * v) & 255;
                float pr = Pre[kk * NSUB + jj48];
                float pi = Pim[kk * NSUB + jj48];
                float tc = twc[t], ts = tws[t];
                gre = fmaf(pr, tc, fmaf(-pi, ts, gre));
                gim = fmaf(pr, ts, fmaf(pi, tc, gim));
            }
            Gre[jj48 * 4 + vv48] = gre;
            Gim[jj48 * 4 + vv48] = gim;
        }
        __syncthreads();
        float wr = c8, wi = s8;
        float ar = 0.0f, ai = 0.0f;
        #pragma unroll 4
        for (int jj = 0; jj < NSUB; ++jj) {
            float gre = Gre[jj * 4 + cc];
            float gim = Gim[jj * 4 + cc];
            ar = fmaf(gre, wr, fmaf(-gim, wi, ar));
            ai = fmaf(gre, wi, fmaf( gim, wr, ai));
            float nwr = fmaf(wr, sc_c, -(wi * sc_s));
            float nwi = fmaf(wr, sc_s,  (wi * sc_c));
            wr = nwr; wi = nwi;
        }
        float val = fmaf(fmaf(ar, ar, ai * ai), scale, bgv);
        atomicAdd(&outb[a * 64 + (cb + cc)], val);
        __syncthreads();
    }
}

extern "C" void kernel_launch(void* const* d_in, const int* in_sizes, int n_in,
                              void* d_out, int out_size, void* d_ws, size_t ws_size,
                              hipStream_t stream)
{
    const float* x  = (const float*)d_in[0];
    const float* y  = (const float*)d_in[1];
    const float* z  = (const float*)d_in[2];
    const float* A  = (const float*)d_in[3];
    const float* bg = (const float*)d_in[4];
    const float* p  = (const float*)d_in[5];
    const float* ph = (const float*)d_in[6];
    float* out = (float*)d_out;
    float* maxws = (float*)d_ws;  // 256 floats

    hipMemsetAsync(d_out, 0, (size_t)out_size * sizeof(float), stream);
    hipMemsetAsync(d_ws, 0, 256 * sizeof(float), stream);

    hipLaunchKernelGGL(psf_max_kernel, dim3(1024), dim3(256), 0, stream,
                       x, y, z, ph, maxws);
    hipLaunchKernelGGL(psf_crop_kernel, dim3(256), dim3(256), 0, stream,
                       x, y, z, A, bg, p, ph, maxws, out);
}

// Round 2
// 177.084 us; speedup vs baseline: 1.5115x; 1.5115x over previous
//
#include <hip/hip_runtime.h>

#define NSUB 48      // pupil nonzero rows/cols are [8,56) of the 64x64 grid
#define J0   8
#define PIF  3.14159265358979323846f

// acc_q += i^{S*q} * (tr,ti), S a literal 0..3 (dead branches fold)
#define QMAC(S, tr, ti, a0r,a0i,a1r,a1i,a2r,a2i,a3r,a3i)                          \
    do {                                                                          \
        a0r += tr; a0i += ti;                                                     \
        if ((S) == 0) { a1r += tr; a1i += ti; a2r += tr; a2i += ti; a3r += tr; a3i += ti; } \
        if ((S) == 1) { a1r -= ti; a1i += tr; a2r -= tr; a2i -= ti; a3r += ti; a3i -= tr; } \
        if ((S) == 2) { a1r -= tr; a1i -= ti; a2r += tr; a2i += ti; a3r -= tr; a3i -= ti; } \
        if ((S) == 3) { a1r += ti; a1i -= tr; a2r -= tr; a2i -= ti; a3r -= ti; a3i += tr; } \
    } while (0)

// Build twiddle table tw[t]=e^{2pi i t/256} and pupil P (k-major: P2k[kk*49+jj],
// pad stride 49 so G-phase reads are near-conflict-free).
__device__ __forceinline__ void build_tw_P(
    int tid, float x, float y, float z,
    const float* __restrict__ phase_in,
    float2* __restrict__ tw, float2* __restrict__ P2k)
{
    {
        float s, c;
        __sincosf((float)tid * (PIF / 128.0f), &s, &c);
        tw[tid] = make_float2(c, s);
    }
    const float c1 = PIF / 128.0f;  // 2*pi/256
    for (int idx = tid; idx < NSUB * NSUB; idx += 256) {
        int jj = idx / NSUB;
        int kk = idx - jj * NSUB;
        int j = jj + J0, k = kk + J0;
        float us = ((float)(2 * j) * (1.0f / 63.0f) - 1.0f) * (4.0f / 3.0f);
        float vs = ((float)(2 * k) * (1.0f / 63.0f) - 1.0f) * (4.0f / 3.0f);
        float r2 = us * us + vs * vs;
        float re = 0.0f, im = 0.0f;
        if (r2 <= 1.0f) {
            float prop = sqrtf(fmaxf(1.0f - r2, 0.0f));
            float ph = phase_in[j * 64 + k] + prop * z
                       - c1 * ((float)(j - 32) * x + (float)(k - 32) * y);
            float s, c;
            __sincosf(ph, &s, &c);
            re = c; im = s;
        }
        P2k[kk * 49 + jj] = make_float2(re, im);
    }
}

// Kernel 1: block = (pair, v-residue r). Covers v = r + 4*vloc (vloc 0..63),
// all 256 u via u-quads. G stage: k-outer/v-inner with v-quad factoring.
// F stage: broadcast b128 G reads, u-quad factoring. atomicMax per-pair max.
__global__ __launch_bounds__(256, 4)
void psf_max_kernel(const float* __restrict__ X, const float* __restrict__ Y,
                    const float* __restrict__ Z,
                    const float* __restrict__ phase_in,
                    float* __restrict__ maxws)
{
    __shared__ float2 tw[256];
    __shared__ __align__(16) float2 PG[NSUB * 66]; // P phase: [kk*49+jj]; G phase: [jj*66+vloc]
    __shared__ float red[4];

    const int tid = threadIdx.x;
    const int pair = blockIdx.x >> 2;
    const int rres = blockIdx.x & 3;
    const float x = X[pair], y = Y[pair], z = Z[pair];

    build_tw_P(tid, x, y, z, phase_in, tw, PG);
    __syncthreads();

    // ---- G phase: 192 threads, thread = (jj, vg). 4 base-v (p) x 4 quads (q).
    const int jj = tid % 48;
    const int vg = tid / 48;
    float gar[4][4], gai[4][4];     // [p][q]
    float gwr[4], gwi[4], gcr[4], gci[4];
    if (tid < 192) {
        _Pragma("unroll")
        for (int p = 0; p < 4; ++p) {
            int vb = rres + 4 * (vg * 4 + p);          // <= 63
            float2 w0 = tw[(J0 * vb) & 255];
            float2 st = tw[vb];
            gwr[p] = w0.x; gwi[p] = w0.y; gcr[p] = st.x; gci[p] = st.y;
            _Pragma("unroll")
            for (int q = 0; q < 4; ++q) { gar[p][q] = 0.0f; gai[p][q] = 0.0f; }
        }
#define GBODY(KK, S) do {                                                         \
        float2 pv = PG[(KK) * 49 + jj];                                           \
        _Pragma("unroll")                                                         \
        for (int p = 0; p < 4; ++p) {                                             \
            float tr = fmaf(-pv.y, gwi[p], pv.x * gwr[p]);                        \
            float ti = fmaf( pv.y, gwr[p], pv.x * gwi[p]);                        \
            QMAC(S, tr, ti, gar[p][0], gai[p][0], gar[p][1], gai[p][1],           \
                            gar[p][2], gai[p][2], gar[p][3], gai[p][3]);          \
            float t  = gwi[p] * gci[p];                                           \
            float nr = fmaf(gwr[p], gcr[p], -t);                                  \
            float ni = fmaf(gwr[p], gci[p], gwi[p] * gcr[p]);                     \
            gwr[p] = nr; gwi[p] = ni;                                             \
        } } while (0)
        #pragma unroll 1
        for (int kk = 0; kk < NSUB; kk += 4) {
            GBODY(kk + 0, 0); GBODY(kk + 1, 1); GBODY(kk + 2, 2); GBODY(kk + 3, 3);
        }
#undef GBODY
    }
    __syncthreads();   // all P reads done; PG may be overwritten as G now
    if (tid < 192) {
        _Pragma("unroll")
        for (int p = 0; p < 4; ++p) {
            _Pragma("unroll")
            for (int q = 0; q < 4; ++q)
                PG[jj * 66 + (vg * 4 + p) + 16 * q] = make_float2(gar[p][q], gai[p][q]);
        }
    }
    __syncthreads();

    // ---- F phase: lane = base u (0..63, quads cover 256), wave wv owns 16 vloc.
    const int lane = tid & 63;
    const int wv = tid >> 6;
    const float2 w0l = tw[(8 * lane) & 255];
    const float2 stl = tw[lane];
    const float crr = stl.x, cii = stl.y;
    float lmax = 0.0f;
    #pragma unroll 1
    for (int p = 0; p < 4; ++p) {
        const int vb = wv * 16 + 4 * p;
        float ar[4][4], ai[4][4];   // [q][vv]
        _Pragma("unroll")
        for (int q = 0; q < 4; ++q) {
            _Pragma("unroll")
            for (int vv = 0; vv < 4; ++vv) { ar[q][vv] = 0.0f; ai[q][vv] = 0.0f; }
        }
        float wr = w0l.x, wi = w0l.y;
#define FMAC1(S, GR, GI, VV) do {                                                 \
        float tr = fmaf(-(GI), wi, (GR) * wr);                                    \
        float ti = fmaf( (GI), wr, (GR) * wi);                                    \
        QMAC(S, tr, ti, ar[0][VV], ai[0][VV], ar[1][VV], ai[1][VV],               \
                        ar[2][VV], ai[2][VV], ar[3][VV], ai[3][VV]);              \
    } while (0)
#define FBODY(JJ, S) do {                                                         \
        const float4 g01 = *(const float4*)&PG[(JJ) * 66 + vb];                   \
        const float4 g23 = *(const float4*)&PG[(JJ) * 66 + vb + 2];               \
        FMAC1(S, g01.x, g01.y, 0); FMAC1(S, g01.z, g01.w, 1);                     \
        FMAC1(S, g23.x, g23.y, 2); FMAC1(S, g23.z, g23.w, 3);                     \
        float t  = wi * cii;                                                      \
        float nr = fmaf(wr, crr, -t);                                             \
        float ni = fmaf(wr, cii, wi * crr);                                       \
        wr = nr; wi = ni;                                                         \
    } while (0)
        #pragma unroll 1
        for (int j4 = 0; j4 < NSUB; j4 += 4) {
            FBODY(j4 + 0, 0); FBODY(j4 + 1, 1); FBODY(j4 + 2, 2); FBODY(j4 + 3, 3);
        }
#undef FBODY
#undef FMAC1
        _Pragma("unroll")
        for (int q = 0; q < 4; ++q) {
            _Pragma("unroll")
            for (int vv = 0; vv < 4; ++vv)
                lmax = fmaxf(lmax, fmaf(ar[q][vv], ar[q][vv], ai[q][vv] * ai[q][vv]));
        }
    }

    for (int off = 32; off > 0; off >>= 1)
        lmax = fmaxf(lmax, __shfl_down(lmax, off, 64));
    if ((tid & 63) == 0) red[tid >> 6] = lmax;
    __syncthreads();
    if (tid == 0) {
        float m = fmaxf(fmaxf(red[0], red[1]), fmaxf(red[2], red[3]));
        atomicMax((unsigned int*)&maxws[pair], __float_as_uint(m));
    }
}

// Kernel 2: block = (pair, 16-column slice of the 64x64 crop). Recomputes only
// cropped field values, normalizes, applies A/bg/mask, atomicAdd over n.
__global__ __launch_bounds__(256, 4)
void psf_crop_kernel(const float* __restrict__ X, const float* __restrict__ Y,
                     const float* __restrict__ Z, const float* __restrict__ Aamp,
                     const float* __restrict__ BG, const float* __restrict__ Pmask,
                     const float* __restrict__ phase_in,
                     const float* __restrict__ maxws,
                     float* __restrict__ out)
{
    const int pair = blockIdx.x >> 2;
    const int vblk = blockIdx.x & 3;
    if (Pmask[pair] <= 0.5f) return;  // uniform across block

    __shared__ float2 tw[256];
    __shared__ __align__(16) float2 PG[NSUB * 49]; // P: [kk*49+jj]; G: [jj*18+vloc] (864 < 2352)

    const int tid = threadIdx.x;
    const float x = X[pair], y = Y[pair], z = Z[pair];
    build_tw_P(tid, x, y, z, phase_in, tw, PG);
    __syncthreads();

    // ---- G: 192 threads, 4 crop-columns each (k-outer, v-inner)
    const int jj = tid % 48;
    const int vg = tid / 48;
    float gr4[4], gi4[4], gwr[4], gwi[4], gcr[4], gci[4];
    if (tid < 192) {
        _Pragma("unroll")
        for (int c = 0; c < 4; ++c) {
            int acol = vblk * 16 + vg * 4 + c;
            int v = (acol + 224) & 255;
            float2 w0 = tw[(J0 * v) & 255];
            float2 st = tw[v];
            gwr[c] = w0.x; gwi[c] = w0.y; gcr[c] = st.x; gci[c] = st.y;
            gr4[c] = 0.0f; gi4[c] = 0.0f;
        }
        #pragma unroll 4
        for (int kk = 0; kk < NSUB; ++kk) {
            float2 pv = PG[kk * 49 + jj];
            _Pragma("unroll")
            for (int c = 0; c < 4; ++c) {
                gr4[c] = fmaf(pv.x, gwr[c], fmaf(-pv.y, gwi[c], gr4[c]));
                gi4[c] = fmaf(pv.x, gwi[c], fmaf( pv.y, gwr[c], gi4[c]));
                float t  = gwi[c] * gci[c];
                float nr = fmaf(gwr[c], gcr[c], -t);
                float ni = fmaf(gwr[c], gci[c], gwi[c] * gcr[c]);
                gwr[c] = nr; gwi[c] = ni;
            }
        }
    }
    __syncthreads();
    if (tid < 192) {
        _Pragma("unroll")
        for (int c = 0; c < 4; ++c)
            PG[jj * 18 + vg * 4 + c] = make_float2(gr4[c], gi4[c]);
    }
    __syncthreads();

    const float scale = Aamp[pair] / maxws[pair];
    const float bgv = BG[pair];

    // ---- F: lane = crop row a, wave wv = 4-column group
    const int lane = tid & 63;
    const int wv = tid >> 6;
    const int u = (lane + 224) & 255;
    const float2 w0l = tw[(8 * u) & 255];
    const float2 stl = tw[u];
    const float crr = stl.x, cii = stl.y;
    const int vb = wv * 4;
    float ar[4], ai[4];
    _Pragma("unroll")
    for (int c = 0; c < 4; ++c) { ar[c] = 0.0f; ai[c] = 0.0f; }
    float wr = w0l.x, wi = w0l.y;
    #pragma unroll 4
    for (int j = 0; j < NSUB; ++j) {
        const float4 g01 = *(const float4*)&PG[j * 18 + vb];
        const float4 g23 = *(const float4*)&PG[j * 18 + vb + 2];
        ar[0] = fmaf(g01.x, wr, fmaf(-g01.y, wi, ar[0]));
        ai[0] = fmaf(g01.x, wi, fmaf( g01.y, wr, ai[0]));
        ar[1] = fmaf(g01.z, wr, fmaf(-g01.w, wi, ar[1]));
        ai[1] = fmaf(g01.z, wi, fmaf( g01.w, wr, ai[1]));
        ar[2] = fmaf(g23.x, wr, fmaf(-g23.y, wi, ar[2]));
        ai[2] = fmaf(g23.x, wi, fmaf( g23.y, wr, ai[2]));
        ar[3] = fmaf(g23.z, wr, fmaf(-g23.w, wi, ar[3]));
        ai[3] = fmaf(g23.z, wi, fmaf( g23.w, wr, ai[3]));
        float t  = wi * cii;
        float nr = fmaf(wr, crr, -t);
        float ni = fmaf(wr, cii, wi * crr);
        wr = nr; wi = ni;
    }

    float* outb = out + ((pair >> 2) << 12) + lane * 64 + vblk * 16 + vb;
    _Pragma("unroll")
    for (int c = 0; c < 4; ++c) {
        float m = fmaf(ar[c], ar[c], ai[c] * ai[c]);
        atomicAdd(&outb[c], fmaf(m, scale, bgv));
    }
}

extern "C" void kernel_launch(void* const* d_in, const int* in_sizes, int n_in,
                              void* d_out, int out_size, void* d_ws, size_t ws_size,
                              hipStream_t stream)
{
    const float* x  = (const float*)d_in[0];
    const float* y  = (const float*)d_in[1];
    const float* z  = (const float*)d_in[2];
    const float* A  = (const float*)d_in[3];
    const float* bg = (const float*)d_in[4];
    const float* p  = (const float*)d_in[5];
    const float* ph = (const float*)d_in[6];
    float* out = (float*)d_out;
    float* maxws = (float*)d_ws;  // 256 floats

    hipMemsetAsync(d_out, 0, (size_t)out_size * sizeof(float), stream);
    hipMemsetAsync(d_ws, 0, 256 * sizeof(float), stream);

    hipLaunchKernelGGL(psf_max_kernel, dim3(1024), dim3(256), 0, stream,
                       x, y, z, ph, maxws);
    hipLaunchKernelGGL(psf_crop_kernel, dim3(1024), dim3(256), 0, stream,
                       x, y, z, A, bg, p, ph, maxws, out);
}

// Round 3
// 107.057 us; speedup vs baseline: 2.5002x; 1.6541x over previous
//
#include <hip/hip_runtime.h>

#define NSUB 48      // pupil nonzero rows/cols are [8,56) of the 64x64 grid
#define J0   8
#define PIF  3.14159265358979323846f

// radix-4 butterfly: A_q = sum_s i^{s*q} B_s   (16 real adds)
#define R4BFLY(B0r,B0i,B1r,B1i,B2r,B2i,B3r,B3i, A0r,A0i,A1r,A1i,A2r,A2i,A3r,A3i) \
  { float c0r=(B0r)+(B2r), c0i=(B0i)+(B2i), d0r=(B0r)-(B2r), d0i=(B0i)-(B2i);     \
    float c1r=(B1r)+(B3r), c1i=(B1i)+(B3i), d1r=(B1r)-(B3r), d1i=(B1i)-(B3i);     \
    A0r=c0r+c1r; A0i=c0i+c1i; A2r=c0r-c1r; A2i=c0i-c1i;                           \
    A1r=d0r-d1i; A1i=d0i+d1r; A3r=d0r+d1i; A3i=d0i-d1r; }

// Build twiddle table tw[t]=e^{2pi i t/256} and pupil P (k-major: P2k[kk*49+jj]).
__device__ __forceinline__ void build_tw_P(
    int tid, float x, float y, float z,
    const float* __restrict__ phase_in,
    float2* __restrict__ tw, float2* __restrict__ P2k)
{
    {
        float s, c;
        __sincosf((float)tid * (PIF / 128.0f), &s, &c);
        tw[tid] = make_float2(c, s);
    }
    const float c1 = PIF / 128.0f;  // 2*pi/256
    for (int idx = tid; idx < NSUB * NSUB; idx += 256) {
        int jj = idx / NSUB;
        int kk = idx - jj * NSUB;
        int j = jj + J0, k = kk + J0;
        float us = ((float)(2 * j) * (1.0f / 63.0f) - 1.0f) * (4.0f / 3.0f);
        float vs = ((float)(2 * k) * (1.0f / 63.0f) - 1.0f) * (4.0f / 3.0f);
        float r2 = us * us + vs * vs;
        float re = 0.0f, im = 0.0f;
        if (r2 <= 1.0f) {
            float prop = sqrtf(fmaxf(1.0f - r2, 0.0f));
            float ph = phase_in[j * 64 + k] + prop * z
                       - c1 * ((float)(j - 32) * x + (float)(k - 32) * y);
            float s, c;
            __sincosf(ph, &s, &c);
            re = c; im = s;
        }
        P2k[kk * 49 + jj] = make_float2(re, im);
    }
}

// Kernel 1: block = (pair, v-residue r). Covers v = r + 4*vloc (vloc 0..63),
// all 256 u via u-quads. Class-sum accumulation (j mod 4 / k mod 4) + one
// radix-4 butterfly per output group. Stashes cropped |F|^2 to global ws.
__global__ __launch_bounds__(256, 4)
void psf_max_kernel(const float* __restrict__ X, const float* __restrict__ Y,
                    const float* __restrict__ Z,
                    const float* __restrict__ phase_in,
                    float* __restrict__ maxws, float* __restrict__ stash,
                    int do_stash)
{
    __shared__ float2 tw[256];
    __shared__ __align__(16) float2 PG[NSUB * 66]; // P: [kk*49+jj]; G: [jj*66+vloc]
    __shared__ float red[4];

    const int tid = threadIdx.x;
    const int pair = blockIdx.x >> 2;
    const int rres = blockIdx.x & 3;
    const float x = X[pair], y = Y[pair], z = Z[pair];

    build_tw_P(tid, x, y, z, phase_in, tw, PG);
    __syncthreads();

    // ---- G phase: 192 threads, thread = (jj, vg). Class sums over k mod 4.
    const int jj = tid % 48;
    const int vg = tid / 48;
    float GqR[4][4], GqI[4][4];     // [p][q]
    if (tid < 192) {
        _Pragma("unroll")
        for (int p = 0; p < 4; ++p) {
            const int vb = rres + 4 * (vg * 4 + p);    // v base (<=63)
            float2 w0 = tw[(J0 * vb) & 255];
            float2 st = tw[vb];
            float wr = w0.x, wi = w0.y;
            const float cr = st.x, ci = st.y;
            float Cr[4] = {0,0,0,0}, Ci[4] = {0,0,0,0};
#define GBODY(KK, S) do {                                                         \
            float2 pv = PG[(KK) * 49 + jj];                                       \
            Cr[S] = fmaf(pv.x, wr, fmaf(-pv.y, wi, Cr[S]));                       \
            Ci[S] = fmaf(pv.x, wi, fmaf( pv.y, wr, Ci[S]));                       \
            float t  = wi * ci;                                                   \
            float nr = fmaf(wr, cr, -t);                                          \
            float ni = fmaf(wr, ci, wi * cr);                                     \
            wr = nr; wi = ni; } while (0)
            #pragma unroll 1
            for (int kk = 0; kk < NSUB; kk += 4) {
                GBODY(kk + 0, 0); GBODY(kk + 1, 1); GBODY(kk + 2, 2); GBODY(kk + 3, 3);
            }
#undef GBODY
            R4BFLY(Cr[0],Ci[0], Cr[1],Ci[1], Cr[2],Ci[2], Cr[3],Ci[3],
                   GqR[p][0],GqI[p][0], GqR[p][1],GqI[p][1],
                   GqR[p][2],GqI[p][2], GqR[p][3],GqI[p][3]);
        }
    }
    __syncthreads();   // all P reads done; PG becomes G storage
    if (tid < 192) {
        _Pragma("unroll")
        for (int p = 0; p < 4; ++p) {
            _Pragma("unroll")
            for (int q = 0; q < 4; ++q)
                PG[jj * 66 + (vg * 4 + p) + 16 * q] = make_float2(GqR[p][q], GqI[p][q]);
        }
    }
    __syncthreads();

    // ---- F phase: lane = base u (quads cover 256 u), wave wv owns 16 vloc.
    const int lane = tid & 63;
    const int wv = tid >> 6;
    const float2 w0l = tw[(8 * lane) & 255];
    const float2 stl = tw[lane];
    const float crr = stl.x, cii = stl.y;
    float lmax = 0.0f;
    #pragma unroll 1
    for (int p = 0; p < 4; ++p) {
        const int vloc0 = wv * 16 + 4 * p;
        const int vb = vloc0;
        float Br[4][4], Bi[4][4];   // [class s][vv]
        _Pragma("unroll")
        for (int s = 0; s < 4; ++s) {
            _Pragma("unroll")
            for (int vv = 0; vv < 4; ++vv) { Br[s][vv] = 0.0f; Bi[s][vv] = 0.0f; }
        }
        float wr = w0l.x, wi = w0l.y;
#define FBODY(JJ, S) do {                                                         \
        const float4 g01 = *(const float4*)&PG[(JJ) * 66 + vb];                   \
        const float4 g23 = *(const float4*)&PG[(JJ) * 66 + vb + 2];               \
        Br[S][0] = fmaf(g01.x, wr, fmaf(-g01.y, wi, Br[S][0]));                   \
        Bi[S][0] = fmaf(g01.x, wi, fmaf( g01.y, wr, Bi[S][0]));                   \
        Br[S][1] = fmaf(g01.z, wr, fmaf(-g01.w, wi, Br[S][1]));                   \
        Bi[S][1] = fmaf(g01.z, wi, fmaf( g01.w, wr, Bi[S][1]));                   \
        Br[S][2] = fmaf(g23.x, wr, fmaf(-g23.y, wi, Br[S][2]));                   \
        Bi[S][2] = fmaf(g23.x, wi, fmaf( g23.y, wr, Bi[S][2]));                   \
        Br[S][3] = fmaf(g23.z, wr, fmaf(-g23.w, wi, Br[S][3]));                   \
        Bi[S][3] = fmaf(g23.z, wi, fmaf( g23.w, wr, Bi[S][3]));                   \
        float t  = wi * cii;                                                      \
        float nr = fmaf(wr, crr, -t);                                             \
        float ni = fmaf(wr, cii, wi * crr);                                       \
        wr = nr; wi = ni; } while (0)
        #pragma unroll 1
        for (int j4 = 0; j4 < NSUB; j4 += 4) {
            FBODY(j4 + 0, 0); FBODY(j4 + 1, 1); FBODY(j4 + 2, 2); FBODY(j4 + 3, 3);
        }
#undef FBODY
        const bool cropcol = (vloc0 < 8) | (vloc0 >= 56);
        _Pragma("unroll")
        for (int vv = 0; vv < 4; ++vv) {
            float a0r,a0i,a1r,a1i,a2r,a2i,a3r,a3i;
            R4BFLY(Br[0][vv],Bi[0][vv], Br[1][vv],Bi[1][vv],
                   Br[2][vv],Bi[2][vv], Br[3][vv],Bi[3][vv],
                   a0r,a0i, a1r,a1i, a2r,a2i, a3r,a3i);
            float m0 = fmaf(a0r, a0r, a0i * a0i);
            float m1 = fmaf(a1r, a1r, a1i * a1i);
            float m2 = fmaf(a2r, a2r, a2i * a2i);
            float m3 = fmaf(a3r, a3r, a3i * a3i);
            lmax = fmaxf(lmax, fmaxf(fmaxf(m0, m1), fmaxf(m2, m3)));
            if (do_stash && cropcol) {
                // crop row a = lane^32 (q=0 half for lanes<32, q=3 half for lanes>=32)
                int c = ((rres + 4 * (vloc0 + vv)) + 32) & 255;   // < 64 when cropcol
                float mc = (lane < 32) ? m0 : m3;
                stash[pair * 4096 + ((lane ^ 32) << 6) + c] = mc;
            }
        }
    }

    for (int off = 32; off > 0; off >>= 1)
        lmax = fmaxf(lmax, __shfl_down(lmax, off, 64));
    if ((tid & 63) == 0) red[tid >> 6] = lmax;
    __syncthreads();
    if (tid == 0) {
        float m = fmaxf(fmaxf(red[0], red[1]), fmaxf(red[2], red[3]));
        atomicMax((unsigned int*)&maxws[pair], __float_as_uint(m));
    }
}

// Kernel 2 (fast path): out[b] = sum_n mask*(stash*A/max) + sum_n mask*bg.
// Fully coalesced, no atomics, writes every output element.
__global__ __launch_bounds__(256)
void combine_kernel(const float* __restrict__ Aamp, const float* __restrict__ BG,
                    const float* __restrict__ Pmask,
                    const float* __restrict__ maxws, const float* __restrict__ stash,
                    float* __restrict__ out)
{
    const int b = blockIdx.x >> 2;
    const int base = (blockIdx.x & 3) * 1024 + threadIdx.x * 4;
    float4 acc = make_float4(0.f, 0.f, 0.f, 0.f);
    float bgtot = 0.0f;
    #pragma unroll
    for (int n = 0; n < 4; ++n) {
        const int pair = b * 4 + n;
        if (Pmask[pair] > 0.5f) {
            const float s = Aamp[pair] / maxws[pair];
            bgtot += BG[pair];
            const float4 v = *(const float4*)(stash + pair * 4096 + base);
            acc.x = fmaf(v.x, s, acc.x);
            acc.y = fmaf(v.y, s, acc.y);
            acc.z = fmaf(v.z, s, acc.z);
            acc.w = fmaf(v.w, s, acc.w);
        }
    }
    *(float4*)(out + b * 4096 + base) =
        make_float4(acc.x + bgtot, acc.y + bgtot, acc.z + bgtot, acc.w + bgtot);
}

// Fallback crop kernel (used only if ws_size is too small for the stash):
// recomputes cropped field values, validated in round 2.
__global__ __launch_bounds__(256, 4)
void psf_crop_kernel(const float* __restrict__ X, const float* __restrict__ Y,
                     const float* __restrict__ Z, const float* __restrict__ Aamp,
                     const float* __restrict__ BG, const float* __restrict__ Pmask,
                     const float* __restrict__ phase_in,
                     const float* __restrict__ maxws,
                     float* __restrict__ out)
{
    const int pair = blockIdx.x >> 2;
    const int vblk = blockIdx.x & 3;
    if (Pmask[pair] <= 0.5f) return;

    __shared__ float2 tw[256];
    __shared__ __align__(16) float2 PG[NSUB * 49];

    const int tid = threadIdx.x;
    const float x = X[pair], y = Y[pair], z = Z[pair];
    build_tw_P(tid, x, y, z, phase_in, tw, PG);
    __syncthreads();

    const int jj = tid % 48;
    const int vg = tid / 48;
    float gr4[4], gi4[4], gwr[4], gwi[4], gcr[4], gci[4];
    if (tid < 192) {
        _Pragma("unroll")
        for (int c = 0; c < 4; ++c) {
            int acol = vblk * 16 + vg * 4 + c;
            int v = (acol + 224) & 255;
            float2 w0 = tw[(J0 * v) & 255];
            float2 st = tw[v];
            gwr[c] = w0.x; gwi[c] = w0.y; gcr[c] = st.x; gci[c] = st.y;
            gr4[c] = 0.0f; gi4[c] = 0.0f;
        }
        #pragma unroll 4
        for (int kk = 0; kk < NSUB; ++kk) {
            float2 pv = PG[kk * 49 + jj];
            _Pragma("unroll")
            for (int c = 0; c < 4; ++c) {
                gr4[c] = fmaf(pv.x, gwr[c], fmaf(-pv.y, gwi[c], gr4[c]));
                gi4[c] = fmaf(pv.x, gwi[c], fmaf( pv.y, gwr[c], gi4[c]));
                float t  = gwi[c] * gci[c];
                float nr = fmaf(gwr[c], gcr[c], -t);
                float ni = fmaf(gwr[c], gci[c], gwi[c] * gcr[c]);
                gwr[c] = nr; gwi[c] = ni;
            }
        }
    }
    __syncthreads();
    if (tid < 192) {
        _Pragma("unroll")
        for (int c = 0; c < 4; ++c)
            PG[jj * 18 + vg * 4 + c] = make_float2(gr4[c], gi4[c]);
    }
    __syncthreads();

    const float scale = Aamp[pair] / maxws[pair];
    const float bgv = BG[pair];

    const int lane = tid & 63;
    const int wv = tid >> 6;
    const int u = (lane + 224) & 255;
    const float2 w0l = tw[(8 * u) & 255];
    const float2 stl = tw[u];
    const float crr = stl.x, cii = stl.y;
    const int vb = wv * 4;
    float ar[4], ai[4];
    _Pragma("unroll")
    for (int c = 0; c < 4; ++c) { ar[c] = 0.0f; ai[c] = 0.0f; }
    float wr = w0l.x, wi = w0l.y;
    #pragma unroll 4
    for (int j = 0; j < NSUB; ++j) {
        const float4 g01 = *(const float4*)&PG[j * 18 + vb];
        const float4 g23 = *(const float4*)&PG[j * 18 + vb + 2];
        ar[0] = fmaf(g01.x, wr, fmaf(-g01.y, wi, ar[0]));
        ai[0] = fmaf(g01.x, wi, fmaf( g01.y, wr, ai[0]));
        ar[1] = fmaf(g01.z, wr, fmaf(-g01.w, wi, ar[1]));
        ai[1] = fmaf(g01.z, wi, fmaf( g01.w, wr, ai[1]));
        ar[2] = fmaf(g23.x, wr, fmaf(-g23.y, wi, ar[2]));
        ai[2] = fmaf(g23.x, wi, fmaf( g23.y, wr, ai[2]));
        ar[3] = fmaf(g23.z, wr, fmaf(-g23.w, wi, ar[3]));
        ai[3] = fmaf(g23.z, wi, fmaf( g23.w, wr, ai[3]));
        float t  = wi * cii;
        float nr = fmaf(wr, crr, -t);
        float ni = fmaf(wr, cii, wi * crr);
        wr = nr; wi = ni;
    }

    float* outb = out + ((pair >> 2) << 12) + lane * 64 + vblk * 16 + vb;
    _Pragma("unroll")
    for (int c = 0; c < 4; ++c) {
        float m = fmaf(ar[c], ar[c], ai[c] * ai[c]);
        atomicAdd(&outb[c], fmaf(m, scale, bgv));
    }
}

extern "C" void kernel_launch(void* const* d_in, const int* in_sizes, int n_in,
                              void* d_out, int out_size, void* d_ws, size_t ws_size,
                              hipStream_t stream)
{
    const float* x  = (const float*)d_in[0];
    const float* y  = (const float*)d_in[1];
    const float* z  = (const float*)d_in[2];
    const float* A  = (const float*)d_in[3];
    const float* bg = (const float*)d_in[4];
    const float* p  = (const float*)d_in[5];
    const float* ph = (const float*)d_in[6];
    float* out = (float*)d_out;
    float* maxws = (float*)d_ws;            // 256 floats
    float* stash = maxws + 256;             // 256 pairs x 64 x 64 floats = 4 MB

    const size_t need = 256u * sizeof(float) + 256u * 4096u * sizeof(float);
    const int do_stash = (ws_size >= need) ? 1 : 0;

    hipMemsetAsync(d_ws, 0, 256 * sizeof(float), stream);

    hipLaunchKernelGGL(psf_max_kernel, dim3(1024), dim3(256), 0, stream,
                       x, y, z, ph, maxws, stash, do_stash);
    if (do_stash) {
        hipLaunchKernelGGL(combine_kernel, dim3(256), dim3(256), 0, stream,
                           A, bg, p, maxws, stash, out);
    } else {
        hipMemsetAsync(d_out, 0, (size_t)out_size * sizeof(float), stream);
        hipLaunchKernelGGL(psf_crop_kernel, dim3(1024), dim3(256), 0, stream,
                           x, y, z, A, bg, p, ph, maxws, out);
    }
}

// Round 4
// 95.357 us; speedup vs baseline: 2.8070x; 1.1227x over previous
//
#include <hip/hip_runtime.h>

#define NSUB 48      // pupil nonzero rows/cols are [8,56) of the 64x64 grid
#define J0   8
#define PIF  3.14159265358979323846f
#define C8   0.70710678118654752440f   // sqrt(2)/2

// radix-4 butterfly: A_q = sum_s i^{s*q} B_s   (16 real adds)
#define R4BFLY(B0r,B0i,B1r,B1i,B2r,B2i,B3r,B3i, A0r,A0i,A1r,A1i,A2r,A2i,A3r,A3i) \
  { float c0r=(B0r)+(B2r), c0i=(B0i)+(B2i), d0r=(B0r)-(B2r), d0i=(B0i)-(B2i);     \
    float c1r=(B1r)+(B3r), c1i=(B1i)+(B3i), d1r=(B1r)-(B3r), d1i=(B1i)-(B3i);     \
    A0r=c0r+c1r; A0i=c0i+c1i; A2r=c0r-c1r; A2i=c0i-c1i;                           \
    A1r=d0r-d1i; A1i=d0i+d1r; A3r=d0r+d1i; A3i=d0i-d1r; }

// Build twiddle table tw[t]=e^{2pi i t/256} and pupil P (k-major: P2k[kk*49+jj]).
__device__ __forceinline__ void build_tw_P(
    int tid, float x, float y, float z,
    const float* __restrict__ phase_in,
    float2* __restrict__ tw, float2* __restrict__ P2k)
{
    {
        float s, c;
        __sincosf((float)tid * (PIF / 128.0f), &s, &c);
        tw[tid] = make_float2(c, s);
    }
    const float c1 = PIF / 128.0f;  // 2*pi/256
    for (int idx = tid; idx < NSUB * NSUB; idx += 256) {
        int jj = idx / NSUB;
        int kk = idx - jj * NSUB;
        int j = jj + J0, k = kk + J0;
        float us = ((float)(2 * j) * (1.0f / 63.0f) - 1.0f) * (4.0f / 3.0f);
        float vs = ((float)(2 * k) * (1.0f / 63.0f) - 1.0f) * (4.0f / 3.0f);
        float r2 = us * us + vs * vs;
        float re = 0.0f, im = 0.0f;
        if (r2 <= 1.0f) {
            float prop = sqrtf(fmaxf(1.0f - r2, 0.0f));
            float ph = phase_in[j * 64 + k] + prop * z
                       - c1 * ((float)(j - 32) * x + (float)(k - 32) * y);
            float s, c;
            __sincosf(ph, &s, &c);
            re = c; im = s;
        }
        P2k[kk * 49 + jj] = make_float2(re, im);
    }
}

// Kernel 1: block = (pair, v-residue r). G: k-mod-4 class sums, shared P loads,
// omega^{4v} rotation. F: radix-8 over j (u = ub + 32t, 32 u-bases x 8 octants).
// Partial per-block max -> plain store maxws4[pair*4+rres]. Stashes cropped |F|^2.
__global__ __launch_bounds__(256, 4)
void psf_max_kernel(const float* __restrict__ X, const float* __restrict__ Y,
                    const float* __restrict__ Z,
                    const float* __restrict__ phase_in,
                    float* __restrict__ maxws4, float* __restrict__ stash,
                    int do_stash)
{
    __shared__ float2 tw[256];
    __shared__ __align__(16) float2 PG[NSUB * 66]; // P: [kk*49+jj]; G: [jj*66+vloc]
    __shared__ float red[4];

    const int tid = threadIdx.x;
    const int pair = blockIdx.x >> 2;
    const int rres = blockIdx.x & 3;
    const float x = X[pair], y = Y[pair], z = Z[pair];

    build_tw_P(tid, x, y, z, phase_in, tw, PG);
    __syncthreads();

    // ---- G accumulate: 192 threads, thread = (jj, vg). For p in [0,4):
    // v = rres + 4*(vg*4+p). Class sums over kk mod 4 with step omega^{4v};
    // one P load serves all 4 p.
    const int jj = tid % 48;
    const int vg = tid / 48;
    float GBr[4][4], GBi[4][4];     // [p][class s]
    if (tid < 192) {
        float gwr[4], gwi[4], gsr[4], gsi[4];
        _Pragma("unroll")
        for (int p = 0; p < 4; ++p) {
            const int v = rres + 4 * (vg * 4 + p);
            float2 st = tw[(4 * v) & 255];
            gsr[p] = st.x; gsi[p] = st.y;
            gwr[p] = 1.0f; gwi[p] = 0.0f;
            _Pragma("unroll")
            for (int s = 0; s < 4; ++s) { GBr[p][s] = 0.0f; GBi[p][s] = 0.0f; }
        }
        #pragma unroll 2
        for (int m = 0; m < 12; ++m) {
            const float2 p0 = PG[(4 * m + 0) * 49 + jj];
            const float2 p1 = PG[(4 * m + 1) * 49 + jj];
            const float2 p2 = PG[(4 * m + 2) * 49 + jj];
            const float2 p3 = PG[(4 * m + 3) * 49 + jj];
            _Pragma("unroll")
            for (int p = 0; p < 4; ++p) {
                const float wr = gwr[p], wi = gwi[p];
                GBr[p][0] = fmaf(p0.x, wr, fmaf(-p0.y, wi, GBr[p][0]));
                GBi[p][0] = fmaf(p0.x, wi, fmaf( p0.y, wr, GBi[p][0]));
                GBr[p][1] = fmaf(p1.x, wr, fmaf(-p1.y, wi, GBr[p][1]));
                GBi[p][1] = fmaf(p1.x, wi, fmaf( p1.y, wr, GBi[p][1]));
                GBr[p][2] = fmaf(p2.x, wr, fmaf(-p2.y, wi, GBr[p][2]));
                GBi[p][2] = fmaf(p2.x, wi, fmaf( p2.y, wr, GBi[p][2]));
                GBr[p][3] = fmaf(p3.x, wr, fmaf(-p3.y, wi, GBr[p][3]));
                GBi[p][3] = fmaf(p3.x, wi, fmaf( p3.y, wr, GBi[p][3]));
                float t  = wi * gsi[p];
                gwr[p] = fmaf(wr, gsr[p], -t);
                gwi[p] = fmaf(wr, gsi[p], wi * gsr[p]);
            }
        }
    }
    __syncthreads();   // all P reads done; PG becomes G storage
    if (tid < 192) {
        _Pragma("unroll")
        for (int p = 0; p < 4; ++p) {
            const int m = vg * 4 + p;
            const int v = rres + 4 * m;
            // T_s = omega^{(s+8)v} * B'_s
            float Tr[4], Ti[4];
            _Pragma("unroll")
            for (int s = 0; s < 4; ++s) {
                float2 u = tw[((s + 8) * v) & 255];
                Tr[s] = GBr[p][s] * u.x - GBi[p][s] * u.y;
                Ti[s] = GBr[p][s] * u.y + GBi[p][s] * u.x;
            }
            float A0r,A0i,A1r,A1i,A2r,A2i,A3r,A3i;
            R4BFLY(Tr[0],Ti[0], Tr[1],Ti[1], Tr[2],Ti[2], Tr[3],Ti[3],
                   A0r,A0i, A1r,A1i, A2r,A2i, A3r,A3i);
            PG[jj * 66 + m +  0] = make_float2(A0r, A0i);
            PG[jj * 66 + m + 16] = make_float2(A1r, A1i);
            PG[jj * 66 + m + 32] = make_float2(A2r, A2i);
            PG[jj * 66 + m + 48] = make_float2(A3r, A3i);
        }
    }
    __syncthreads();

    // ---- F phase, radix-8: thread = (ub 0..31, vgrp 0..7). u = ub + 32t.
    // Class sums over jj mod 8 with weight omega^{(jj+8)ub}; one butterfly / 8 u.
    const int ub = tid & 31;
    const int vgrp = tid >> 5;
    const float2 w0l = tw[(8 * ub) & 255];
    const float2 stl = tw[ub];
    const float crr = stl.x, cii = stl.y;
    float lmax = 0.0f;
    #pragma unroll 1
    for (int c2 = 0; c2 < 2; ++c2) {
        const int vb = vgrp * 8 + c2 * 4;     // vloc base (4 consecutive vloc)
        float FBr[8][4], FBi[8][4];           // [class][vv]
        _Pragma("unroll")
        for (int s = 0; s < 8; ++s) {
            _Pragma("unroll")
            for (int vv = 0; vv < 4; ++vv) { FBr[s][vv] = 0.0f; FBi[s][vv] = 0.0f; }
        }
        float wr = w0l.x, wi = w0l.y;
#define FBODY(JJ, S) do {                                                         \
        const float4 g01 = *(const float4*)&PG[(JJ) * 66 + vb];                   \
        const float4 g23 = *(const float4*)&PG[(JJ) * 66 + vb + 2];               \
        FBr[S][0] = fmaf(g01.x, wr, fmaf(-g01.y, wi, FBr[S][0]));                 \
        FBi[S][0] = fmaf(g01.x, wi, fmaf( g01.y, wr, FBi[S][0]));                 \
        FBr[S][1] = fmaf(g01.z, wr, fmaf(-g01.w, wi, FBr[S][1]));                 \
        FBi[S][1] = fmaf(g01.z, wi, fmaf( g01.w, wr, FBi[S][1]));                 \
        FBr[S][2] = fmaf(g23.x, wr, fmaf(-g23.y, wi, FBr[S][2]));                 \
        FBi[S][2] = fmaf(g23.x, wi, fmaf( g23.y, wr, FBi[S][2]));                 \
        FBr[S][3] = fmaf(g23.z, wr, fmaf(-g23.w, wi, FBr[S][3]));                 \
        FBi[S][3] = fmaf(g23.z, wi, fmaf( g23.w, wr, FBi[S][3]));                 \
        float t  = wi * cii;                                                      \
        float nr = fmaf(wr, crr, -t);                                             \
        float ni = fmaf(wr, cii, wi * crr);                                       \
        wr = nr; wi = ni; } while (0)
        #pragma unroll 1
        for (int j8 = 0; j8 < NSUB; j8 += 8) {
            FBODY(j8 + 0, 0); FBODY(j8 + 1, 1); FBODY(j8 + 2, 2); FBODY(j8 + 3, 3);
            FBODY(j8 + 4, 4); FBODY(j8 + 5, 5); FBODY(j8 + 6, 6); FBODY(j8 + 7, 7);
        }
#undef FBODY
        const bool cropcol = (vb < 8) | (vb >= 56);
        _Pragma("unroll")
        for (int vv = 0; vv < 4; ++vv) {
            float E0r,E0i,E1r,E1i,E2r,E2i,E3r,E3i;
            float O0r,O0i,O1r,O1i,O2r,O2i,O3r,O3i;
            R4BFLY(FBr[0][vv],FBi[0][vv], FBr[2][vv],FBi[2][vv],
                   FBr[4][vv],FBi[4][vv], FBr[6][vv],FBi[6][vv],
                   E0r,E0i, E1r,E1i, E2r,E2i, E3r,E3i);
            R4BFLY(FBr[1][vv],FBi[1][vv], FBr[3][vv],FBi[3][vv],
                   FBr[5][vv],FBi[5][vv], FBr[7][vv],FBi[7][vv],
                   O0r,O0i, O1r,O1i, O2r,O2i, O3r,O3i);
            // F_t = E[t mod 4] + e^{2 pi i t/8} O[t mod 4]
            float F0r = E0r + O0r, F0i = E0i + O0i;
            float F4r = E0r - O0r, F4i = E0i - O0i;
            float F2r = E2r - O2i, F2i = E2i + O2r;
            float F6r = E2r + O2i, F6i = E2i - O2r;
            float p1r = C8 * (O1r - O1i), p1i = C8 * (O1r + O1i);
            float F1r = E1r + p1r, F1i = E1i + p1i;
            float F5r = E1r - p1r, F5i = E1i - p1i;
            float q3r = -C8 * (O3r + O3i), q3i = C8 * (O3r - O3i);
            float F3r = E3r + q3r, F3i = E3i + q3i;
            float F7r = E3r - q3r, F7i = E3i - q3i;
            float m0 = fmaf(F0r, F0r, F0i * F0i);
            float m1 = fmaf(F1r, F1r, F1i * F1i);
            float m2 = fmaf(F2r, F2r, F2i * F2i);
            float m3 = fmaf(F3r, F3r, F3i * F3i);
            float m4 = fmaf(F4r, F4r, F4i * F4i);
            float m5 = fmaf(F5r, F5r, F5i * F5i);
            float m6 = fmaf(F6r, F6r, F6i * F6i);
            float m7 = fmaf(F7r, F7r, F7i * F7i);
            lmax = fmaxf(lmax, fmaxf(fmaxf(fmaxf(m0, m1), fmaxf(m2, m3)),
                                     fmaxf(fmaxf(m4, m5), fmaxf(m6, m7))));
            if (do_stash && cropcol) {
                // crop rows: t=0 -> a=ub+32 (val m0); t=7 -> a=ub (val m7)
                const int c = ((rres + 4 * (vb + vv)) + 32) & 255;  // crop col < 64
                stash[pair * 4096 + ((ub + 32) << 6) + c] = m0;
                stash[pair * 4096 + (ub << 6) + c] = m7;
            }
        }
    }

    for (int off = 32; off > 0; off >>= 1)
        lmax = fmaxf(lmax, __shfl_down(lmax, off, 64));
    if ((tid & 63) == 0) red[tid >> 6] = lmax;
    __syncthreads();
    if (tid == 0) {
        maxws4[blockIdx.x] = fmaxf(fmaxf(red[0], red[1]), fmaxf(red[2], red[3]));
    }
}

// Kernel 2 (fast path): out[b] = sum_n mask*(stash*A/max) + sum_n mask*bg.
__global__ __launch_bounds__(256)
void combine_kernel(const float* __restrict__ Aamp, const float* __restrict__ BG,
                    const float* __restrict__ Pmask,
                    const float* __restrict__ maxws4, const float* __restrict__ stash,
                    float* __restrict__ out)
{
    const int b = blockIdx.x >> 2;
    const int base = (blockIdx.x & 3) * 1024 + threadIdx.x * 4;
    float4 acc = make_float4(0.f, 0.f, 0.f, 0.f);
    float bgtot = 0.0f;
    #pragma unroll
    for (int n = 0; n < 4; ++n) {
        const int pair = b * 4 + n;
        if (Pmask[pair] > 0.5f) {
            const float4 m4 = *(const float4*)&maxws4[pair * 4];
            const float mx = fmaxf(fmaxf(m4.x, m4.y), fmaxf(m4.z, m4.w));
            const float s = Aamp[pair] / mx;
            bgtot += BG[pair];
            const float4 v = *(const float4*)(stash + pair * 4096 + base);
            acc.x = fmaf(v.x, s, acc.x);
            acc.y = fmaf(v.y, s, acc.y);
            acc.z = fmaf(v.z, s, acc.z);
            acc.w = fmaf(v.w, s, acc.w);
        }
    }
    *(float4*)(out + b * 4096 + base) =
        make_float4(acc.x + bgtot, acc.y + bgtot, acc.z + bgtot, acc.w + bgtot);
}

// Fallback crop kernel (only if ws too small for the stash): recomputes the
// cropped field values directly (validated in round 2), reads partial maxes.
__global__ __launch_bounds__(256, 4)
void psf_crop_kernel(const float* __restrict__ X, const float* __restrict__ Y,
                     const float* __restrict__ Z, const float* __restrict__ Aamp,
                     const float* __restrict__ BG, const float* __restrict__ Pmask,
                     const float* __restrict__ phase_in,
                     const float* __restrict__ maxws4,
                     float* __restrict__ out)
{
    const int pair = blockIdx.x >> 2;
    const int vblk = blockIdx.x & 3;
    if (Pmask[pair] <= 0.5f) return;

    __shared__ float2 tw[256];
    __shared__ __align__(16) float2 PG[NSUB * 49];

    const int tid = threadIdx.x;
    const float x = X[pair], y = Y[pair], z = Z[pair];
    build_tw_P(tid, x, y, z, phase_in, tw, PG);
    __syncthreads();

    const int jj = tid % 48;
    const int vg = tid / 48;
    float gr4[4], gi4[4], gwr[4], gwi[4], gcr[4], gci[4];
    if (tid < 192) {
        _Pragma("unroll")
        for (int c = 0; c < 4; ++c) {
            int acol = vblk * 16 + vg * 4 + c;
            int v = (acol + 224) & 255;
            float2 w0 = tw[(J0 * v) & 255];
            float2 st = tw[v];
            gwr[c] = w0.x; gwi[c] = w0.y; gcr[c] = st.x; gci[c] = st.y;
            gr4[c] = 0.0f; gi4[c] = 0.0f;
        }
        #pragma unroll 4
        for (int kk = 0; kk < NSUB; ++kk) {
            float2 pv = PG[kk * 49 + jj];
            _Pragma("unroll")
            for (int c = 0; c < 4; ++c) {
                gr4[c] = fmaf(pv.x, gwr[c], fmaf(-pv.y, gwi[c], gr4[c]));
                gi4[c] = fmaf(pv.x, gwi[c], fmaf( pv.y, gwr[c], gi4[c]));
                float t  = gwi[c] * gci[c];
                float nr = fmaf(gwr[c], gcr[c], -t);
                float ni = fmaf(gwr[c], gci[c], gwi[c] * gcr[c]);
                gwr[c] = nr; gwi[c] = ni;
            }
        }
    }
    __syncthreads();
    if (tid < 192) {
        _Pragma("unroll")
        for (int c = 0; c < 4; ++c)
            PG[jj * 18 + vg * 4 + c] = make_float2(gr4[c], gi4[c]);
    }
    __syncthreads();

    const float4 m4 = *(const float4*)&maxws4[pair * 4];
    const float mx = fmaxf(fmaxf(m4.x, m4.y), fmaxf(m4.z, m4.w));
    const float scale = Aamp[pair] / mx;
    const float bgv = BG[pair];

    const int lane = tid & 63;
    const int wv = tid >> 6;
    const int u = (lane + 224) & 255;
    const float2 w0l = tw[(8 * u) & 255];
    const float2 stl = tw[u];
    const float crr = stl.x, cii = stl.y;
    const int vb = wv * 4;
    float ar[4], ai[4];
    _Pragma("unroll")
    for (int c = 0; c < 4; ++c) { ar[c] = 0.0f; ai[c] = 0.0f; }
    float wr = w0l.x, wi = w0l.y;
    #pragma unroll 4
    for (int j = 0; j < NSUB; ++j) {
        const float4 g01 = *(const float4*)&PG[j * 18 + vb];
        const float4 g23 = *(const float4*)&PG[j * 18 + vb + 2];
        ar[0] = fmaf(g01.x, wr, fmaf(-g01.y, wi, ar[0]));
        ai[0] = fmaf(g01.x, wi, fmaf( g01.y, wr, ai[0]));
        ar[1] = fmaf(g01.z, wr, fmaf(-g01.w, wi, ar[1]));
        ai[1] = fmaf(g01.z, wi, fmaf( g01.w, wr, ai[1]));
        ar[2] = fmaf(g23.x, wr, fmaf(-g23.y, wi, ar[2]));
        ai[2] = fmaf(g23.x, wi, fmaf( g23.y, wr, ai[2]));
        ar[3] = fmaf(g23.z, wr, fmaf(-g23.w, wi, ar[3]));
        ai[3] = fmaf(g23.z, wi, fmaf( g23.w, wr, ai[3]));
        float t  = wi * cii;
        float nr = fmaf(wr, crr, -t);
        float ni = fmaf(wr, cii, wi * crr);
        wr = nr; wi = ni;
    }

    float* outb = out + ((pair >> 2) << 12) + lane * 64 + vblk * 16 + vb;
    _Pragma("unroll")
    for (int c = 0; c < 4; ++c) {
        float m = fmaf(ar[c], ar[c], ai[c] * ai[c]);
        atomicAdd(&outb[c], fmaf(m, scale, bgv));
    }
}

extern "C" void kernel_launch(void* const* d_in, const int* in_sizes, int n_in,
                              void* d_out, int out_size, void* d_ws, size_t ws_size,
                              hipStream_t stream)
{
    const float* x  = (const float*)d_in[0];
    const float* y  = (const float*)d_in[1];
    const float* z  = (const float*)d_in[2];
    const float* A  = (const float*)d_in[3];
    const float* bg = (const float*)d_in[4];
    const float* p  = (const float*)d_in[5];
    const float* ph = (const float*)d_in[6];
    float* out = (float*)d_out;
    float* maxws4 = (float*)d_ws;           // 1024 floats (4 partial maxes / pair)
    float* stash  = maxws4 + 1024;          // 256 pairs x 64 x 64 floats = 4 MB

    const size_t need = 1024u * sizeof(float) + 256u * 4096u * sizeof(float);
    const int do_stash = (ws_size >= need) ? 1 : 0;

    hipLaunchKernelGGL(psf_max_kernel, dim3(1024), dim3(256), 0, stream,
                       x, y, z, ph, maxws4, stash, do_stash);
    if (do_stash) {
        hipLaunchKernelGGL(combine_kernel, dim3(256), dim3(256), 0, stream,
                           A, bg, p, maxws4, stash, out);
    } else {
        hipMemsetAsync(d_out, 0, (size_t)out_size * sizeof(float), stream);
        hipLaunchKernelGGL(psf_crop_kernel, dim3(1024), dim3(256), 0, stream,
                           x, y, z, A, bg, p, ph, maxws4, out);
    }
}